// Round 11
// baseline (264.008 us; speedup 1.0000x reference)
//
#include <hip/hip_runtime.h>
#include <hip/hip_bf16.h>
#include <math.h>
#include <stdint.h>

typedef __attribute__((ext_vector_type(8))) short short8;
typedef __attribute__((ext_vector_type(16))) float f32x16;

__device__ inline short f2bf(float x) {
  union { float f; uint32_t u; } c; c.f = x;
  uint32_t r = (c.u + 0x7FFFu + ((c.u >> 16) & 1u)) >> 16;
  return (short)(uint16_t)r;
}
__device__ inline float bf2f(short s) {
  union { uint32_t u; float f; } c; c.u = ((uint32_t)(uint16_t)s) << 16;
  return c.f;
}

__device__ inline void gload16(const short* src, const char* ldsdst) {
  __builtin_amdgcn_global_load_lds(
      (const __attribute__((address_space(1))) void*)src,
      (__attribute__((address_space(3))) void*)ldsdst, 16, 0, 0);
}

#define BAR __builtin_amdgcn_s_barrier()
#define VMC(n) asm volatile("s_waitcnt vmcnt(" #n ")" ::: "memory")

// ---------------- prep: f32 -> bf16 for X and Kp in one launch ----------------
__global__ void cvt2_kernel(const float* __restrict__ X, const float* __restrict__ Kp,
                            short* __restrict__ Xb, short* __restrict__ Kb,
                            int n8x, int n8tot) {
  int i = blockIdx.x * blockDim.x + threadIdx.x;
  if (i >= n8tot) return;
  const float* src = (i < n8x) ? X + (size_t)i * 8 : Kp + (size_t)(i - n8x) * 8;
  short* dst = (i < n8x) ? Xb + (size_t)i * 8 : Kb + (size_t)(i - n8x) * 8;
  const float4* p = (const float4*)src;
  float4 a = p[0], b = p[1];
  short8 o;
  o[0] = f2bf(a.x); o[1] = f2bf(a.y); o[2] = f2bf(a.z); o[3] = f2bf(a.w);
  o[4] = f2bf(b.x); o[5] = f2bf(b.y); o[6] = f2bf(b.z); o[7] = f2bf(b.w);
  *(short8*)dst = o;
}

// ---------------- prep: V[4096,1024] f32 -> Vt[1024,4096] bf16 ----------------
__global__ void transpose_bf16_kernel(const float* __restrict__ V,
                                      short* __restrict__ Vt,
                                      int rows, int cols) {
  __shared__ float tile[64][65];
  int n0 = blockIdx.x * 64;
  int d0 = blockIdx.y * 64;
  int t = threadIdx.x;
#pragma unroll
  for (int r = 0; r < 16; ++r) {
    int idx = t + 256 * r;
    int rr = idx >> 6, cc = idx & 63;
    tile[rr][cc] = V[(size_t)(n0 + rr) * cols + d0 + cc];
  }
  __syncthreads();
#pragma unroll
  for (int r = 0; r < 16; ++r) {
    int idx = t + 256 * r;
    int dd = idx >> 6, nn = idx & 63;
    Vt[(size_t)(d0 + dd) * rows + n0 + nn] = f2bf(tile[nn][dd]);
  }
}

// ======== GEMM1: S[8192,4096](bf16) = Xb x Kb^T — 32x32x16 MFMA ========
// BM=BN=256, BK=64, 8 waves (2x4), dbuf LDS 128 KiB, R5-verified sync:
// 2 barriers + 2 counted vmcnt per K-tile, each VMC immediately before BAR.
__global__ __launch_bounds__(512, 2) void gemm1_kernel(
    const short* __restrict__ A, const short* __restrict__ B,
    short* __restrict__ S, float* __restrict__ rowss) {
  constexpr int K = 1024, N = 4096, NT = K / 64;
  __shared__ char lds[2 * 65536];  // per buf: A 32K @0, B 32K @32768
  const int t = threadIdx.x, lane = t & 63, w = t >> 6;
  const int wm = w >> 2, wn = w & 3;
  const int r32 = lane & 31, l5 = lane >> 5;
  const int bid = blockIdx.x;
  const int id2 = (bid & 7) * 64 + (bid >> 3);  // 512 blocks, bijective
  const int row0 = (id2 >> 4) * 256, col0 = (id2 & 15) * 256;

  // staging (R5-verified, 0 conflicts): thread t -> LDS byte t*16 of a
  // 64-row round; content = logical 16B-slot (t&7)^((row)&7), row = t>>3
  const int sxor = ((t & 7) ^ ((t >> 3) & 7)) * 8;
  const short* gA = A + (size_t)(row0 + (t >> 3)) * K + sxor;
  const short* gB = B + (size_t)(col0 + (t >> 3)) * K + sxor;

  auto stageA = [&](int buf, int frow, int kt) {
#pragma unroll
    for (int r = 0; r < 2; ++r)
      gload16(gA + (size_t)(frow + r * 64) * K + kt,
              &lds[buf * 65536 + (frow + r * 64) * 128 + t * 16]);
  };
  auto stageB = [&](int buf, int frow, int kt) {
#pragma unroll
    for (int r = 0; r < 2; ++r)
      gload16(gB + (size_t)(frow + r * 64) * K + kt,
              &lds[buf * 65536 + 32768 + (frow + r * 64) * 128 + t * 16]);
  };

  // reads: logical slot q = c*2 + l5 of row r lives at slot q ^ (r&7); r&7==r32&7
  int qb[4];
#pragma unroll
  for (int c = 0; c < 4; ++c) qb[c] = ((c * 2 + l5) ^ (r32 & 7)) << 4;

  short8 a[2][4], b[2][4];
  auto lda = [&](int buf, int mh) {
#pragma unroll
    for (int fr = 0; fr < 2; ++fr)
#pragma unroll
      for (int c = 0; c < 4; ++c) {
        const int row = mh * 128 + wm * 64 + fr * 32 + r32;
        a[fr][c] = *(const short8*)&lds[buf * 65536 + row * 128 + qb[c]];
      }
  };
  auto ldb = [&](int buf, int nh) {
#pragma unroll
    for (int c = 0; c < 4; ++c) {
      const int col = wn * 64 + nh * 32 + r32;
      b[nh][c] = *(const short8*)&lds[buf * 65536 + 32768 + col * 128 + qb[c]];
    }
  };

  f32x16 acc[4][2] = {};  // [mh*2+fr][nh]
  auto MFQ = [&](int mh, int nh) {
    __builtin_amdgcn_s_setprio(1);
#pragma unroll
    for (int c = 0; c < 4; ++c)
#pragma unroll
      for (int fr = 0; fr < 2; ++fr)
        acc[mh * 2 + fr][nh] = __builtin_amdgcn_mfma_f32_32x32x16_bf16(
            a[fr][c], b[nh][c], acc[mh * 2 + fr][nh], 0, 0, 0);
    __builtin_amdgcn_s_setprio(0);
  };

  // prologue: stage tile 0 [Alo,Blo,Bhi,Ahi]; certify Alo,Blo,Bhi (6 of 8)
  stageA(0, 0, 0);
  stageB(0, 0, 0);
  stageB(0, 128, 0);
  stageA(0, 128, 0);
  VMC(2);
  BAR;

  for (int tb = 0; tb < NT; tb += 2) {
#pragma unroll
    for (int u = 0; u < 2; ++u) {
      const int T = tb + u, buf = u, nbuf = u ^ 1;
      const int kt1 = (T + 1) * 64;
      const bool more = (T + 1 < NT);
      // p1: (m0,n0) — Alo,Blo,Bhi certified at boundary
      lda(buf, 0); ldb(buf, 0);
      if (more) stageA(nbuf, 0, kt1);
      MFQ(0, 0);
      // p2: (m0,n1)
      ldb(buf, 1);
      if (more) stageB(nbuf, 0, kt1);
      MFQ(0, 1);
      // mid-tile: certify Ahi(t) across waves
      if (more) { VMC(4); } else { VMC(0); }
      BAR;
      // p3: (m1,n1)
      lda(buf, 1);
      if (more) stageB(nbuf, 128, kt1);
      MFQ(1, 1);
      // p4: (m1,n0)
      if (more) stageA(nbuf, 128, kt1);
      MFQ(1, 0);
      if (more) {
        VMC(2);  // certify Alo,Blo,Bhi(t+1)
        BAR;
      }
    }
  }

  // epilogue 32x32 C/D: col = lane&31, row = (j&3) + 8*(j>>2) + 4*l5
#pragma unroll
  for (int mf = 0; mf < 4; ++mf) {
    const int mh = mf >> 1, fr = mf & 1;
#pragma unroll
    for (int j = 0; j < 16; ++j) {
      const int row = row0 + mh * 128 + wm * 64 + fr * 32 +
                      (j & 3) + 8 * (j >> 2) + 4 * l5;
      float ss = 0.f;
#pragma unroll
      for (int nh = 0; nh < 2; ++nh) {
        const float v = acc[mf][nh][j];
        ss += v * v;
        S[(size_t)row * N + col0 + wn * 64 + nh * 32 + r32] = f2bf(v);
      }
      ss += __shfl_xor(ss, 1);
      ss += __shfl_xor(ss, 2);
      ss += __shfl_xor(ss, 4);
      ss += __shfl_xor(ss, 8);
      ss += __shfl_xor(ss, 16);
      if (r32 == 0) atomicAdd(&rowss[row], ss);
    }
  }
}

// ======== GEMM2: out[8192,1024](f32) = S x Vt^T — 32x32x16 MFMA ========
// BM=256, BN=128, BK=64, 8 waves (4x2), dbuf LDS 96 KiB, R5-verified sync.
__global__ __launch_bounds__(512, 2) void gemm2_kernel(
    const short* __restrict__ A, const short* __restrict__ B,
    float* __restrict__ C) {
  constexpr int K = 4096, N = 1024, NT = K / 64;
  __shared__ char lds[2 * 49152];  // per buf: A 32K @0, B 16K @32768
  const int t = threadIdx.x, lane = t & 63, w = t >> 6;
  const int wm = w >> 1, wn = w & 1;
  const int r32 = lane & 31, l5 = lane >> 5;
  const int bid = blockIdx.x;
  const int id2 = (bid & 7) * 32 + (bid >> 3);  // 256 blocks
  const int row0 = (id2 >> 3) * 256, col0 = (id2 & 7) * 128;

  const int sxor = ((t & 7) ^ ((t >> 3) & 7)) * 8;
  const short* gA = A + (size_t)(row0 + (t >> 3)) * K + sxor;
  const short* gB = B + (size_t)(col0 + (t >> 3)) * K + sxor;

  auto stageAr = [&](int buf, int fr, int kt) {
    gload16(gA + (size_t)(fr)*K + kt, &lds[buf * 49152 + fr * 128 + t * 16]);
  };
  auto stageB = [&](int buf, int kt) {
#pragma unroll
    for (int r = 0; r < 2; ++r)
      gload16(gB + (size_t)(r * 64) * K + kt,
              &lds[buf * 49152 + 32768 + r * 8192 + t * 16]);
  };

  int qb[4];
#pragma unroll
  for (int c = 0; c < 4; ++c) qb[c] = ((c * 2 + l5) ^ (r32 & 7)) << 4;

  short8 a[4], b[2][4];
  auto lda = [&](int buf, int mh) {
#pragma unroll
    for (int c = 0; c < 4; ++c) {
      const int row = mh * 128 + wm * 32 + r32;
      a[c] = *(const short8*)&lds[buf * 49152 + row * 128 + qb[c]];
    }
  };
  auto ldb = [&](int buf) {
#pragma unroll
    for (int nf = 0; nf < 2; ++nf)
#pragma unroll
      for (int c = 0; c < 4; ++c) {
        const int col = wn * 64 + nf * 32 + r32;
        b[nf][c] = *(const short8*)&lds[buf * 49152 + 32768 + col * 128 + qb[c]];
      }
  };

  f32x16 acc[2][2] = {};  // [mh][nf]
  auto MF = [&](int mh) {
    __builtin_amdgcn_s_setprio(1);
#pragma unroll
    for (int c = 0; c < 4; ++c)
#pragma unroll
      for (int nf = 0; nf < 2; ++nf)
        acc[mh][nf] = __builtin_amdgcn_mfma_f32_32x32x16_bf16(
            a[c], b[nf][c], acc[mh][nf], 0, 0, 0);
    __builtin_amdgcn_s_setprio(0);
  };

  // prologue: stage tile 0 [B,A0,A1,A2,A3]; certify B,A0,A1 (4 of 6)
  stageB(0, 0);
  stageAr(0, 0, 0);
  stageAr(0, 64, 0);
  stageAr(0, 128, 0);
  stageAr(0, 192, 0);
  VMC(2);
  BAR;

  for (int tb = 0; tb < NT; tb += 2) {
#pragma unroll
    for (int u = 0; u < 2; ++u) {
      const int T = tb + u, buf = u, nbuf = u ^ 1;
      const int kt1 = (T + 1) * 64;
      const bool more = (T + 1 < NT);
      // p1: m-half 0 (rows wm*32 ⊂ A0∪A64; all B) — certified at boundary
      ldb(buf); lda(buf, 0);
      if (more) { stageB(nbuf, kt1); stageAr(nbuf, 0, kt1); stageAr(nbuf, 64, kt1); }
      MF(0);
      if (more) { VMC(4); } else { VMC(0); }  // certify A128,A192(t)
      BAR;
      // p2: m-half 1
      lda(buf, 1);
      if (more) { stageAr(nbuf, 128, kt1); stageAr(nbuf, 192, kt1); }
      MF(1);
      if (more) {
        VMC(2);  // certify B,A0,A64(t+1)
        BAR;
      }
    }
  }

#pragma unroll
  for (int mh = 0; mh < 2; ++mh)
#pragma unroll
    for (int j = 0; j < 16; ++j) {
      const int row = row0 + mh * 128 + wm * 32 + (j & 3) + 8 * (j >> 2) + 4 * l5;
#pragma unroll
      for (int nf = 0; nf < 2; ++nf)
        C[(size_t)row * N + col0 + wn * 64 + nf * 32 + r32] = acc[mh][nf][j];
    }
}

// ---------------- normalize + exact GELU ----------------
__global__ void norm_gelu_kernel(short* __restrict__ S,
                                 const float* __restrict__ rowss, int total8) {
  int i = blockIdx.x * blockDim.x + threadIdx.x;
  if (i >= total8) return;
  size_t base = (size_t)i * 8;
  int row = (int)(base >> 12);
  float scale = 64.0f * rsqrtf(rowss[row]);
  short8 v = *(short8*)(S + base);
  short8 o;
#pragma unroll
  for (int k = 0; k < 8; ++k) {
    float x = bf2f(v[k]) * scale;
    float gl = 0.5f * x * (1.0f + erff(x * 0.70710678118654752f));
    o[k] = f2bf(gl);
  }
  *(short8*)(S + base) = o;
}

extern "C" void kernel_launch(void* const* d_in, const int* in_sizes, int n_in,
                              void* d_out, int out_size, void* d_ws,
                              size_t ws_size, hipStream_t stream) {
  const float* X = (const float*)d_in[0];
  const float* Kp = (const float*)d_in[1];
  const float* Vp = (const float*)d_in[2];
  float* out = (float*)d_out;

  const int M = 8192, D1 = 1024, Nn = 4096, D2 = 1024;

  char* ws = (char*)d_ws;
  short* Xb = (short*)ws; ws += (size_t)M * D1 * 2;
  short* Kb = (short*)ws; ws += (size_t)Nn * D1 * 2;
  short* Vt = (short*)ws; ws += (size_t)D2 * Nn * 2;
  short* S  = (short*)ws; ws += (size_t)M * Nn * 2;
  float* rowss = (float*)ws;
  (void)ws_size;

  hipMemsetAsync(rowss, 0, M * sizeof(float), stream);
  const int n8x = M * D1 / 8, n8k = Nn * D1 / 8;
  cvt2_kernel<<<(n8x + n8k + 255) / 256, 256, 0, stream>>>(X, Kp, Xb, Kb, n8x, n8x + n8k);
  transpose_bf16_kernel<<<dim3(Nn / 64, D2 / 64), 256, 0, stream>>>(Vp, Vt, Nn, D2);

  gemm1_kernel<<<512, 512, 0, stream>>>(Xb, Kb, S, rowss);
  norm_gelu_kernel<<<(M * Nn / 8 + 255) / 256, 256, 0, stream>>>(S, rowss, M * Nn / 8);
  gemm2_kernel<<<256, 512, 0, stream>>>(S, Vt, out);
}

// Round 12
// 198.079 us; speedup vs baseline: 1.3328x; 1.3328x over previous
//
#include <hip/hip_runtime.h>
#include <hip/hip_bf16.h>
#include <math.h>
#include <stdint.h>

typedef __attribute__((ext_vector_type(8))) short short8;
typedef __attribute__((ext_vector_type(4))) float f32x4;

__device__ inline short f2bf(float x) {
  union { float f; uint32_t u; } c; c.f = x;
  uint32_t r = (c.u + 0x7FFFu + ((c.u >> 16) & 1u)) >> 16;
  return (short)(uint16_t)r;
}
__device__ inline float bf2f(short s) {
  union { uint32_t u; float f; } c; c.u = ((uint32_t)(uint16_t)s) << 16;
  return c.f;
}

__device__ inline void gload16(const short* src, const char* ldsdst) {
  __builtin_amdgcn_global_load_lds(
      (const __attribute__((address_space(1))) void*)src,
      (__attribute__((address_space(3))) void*)ldsdst, 16, 0, 0);
}

#define BAR __builtin_amdgcn_s_barrier()
#define VMC(n) asm volatile("s_waitcnt vmcnt(" #n ")" ::: "memory")
#define LGKM0                                          \
  do {                                                 \
    asm volatile("s_waitcnt lgkmcnt(0)" ::: "memory"); \
    __builtin_amdgcn_sched_barrier(0);                 \
  } while (0)

// ---------------- prep: f32 -> bf16 for X and Kp in one launch ----------------
__global__ void cvt2_kernel(const float* __restrict__ X, const float* __restrict__ Kp,
                            short* __restrict__ Xb, short* __restrict__ Kb,
                            int n8x, int n8tot) {
  int i = blockIdx.x * blockDim.x + threadIdx.x;
  if (i >= n8tot) return;
  const float* src = (i < n8x) ? X + (size_t)i * 8 : Kp + (size_t)(i - n8x) * 8;
  short* dst = (i < n8x) ? Xb + (size_t)i * 8 : Kb + (size_t)(i - n8x) * 8;
  const float4* p = (const float4*)src;
  float4 a = p[0], b = p[1];
  short8 o;
  o[0] = f2bf(a.x); o[1] = f2bf(a.y); o[2] = f2bf(a.z); o[3] = f2bf(a.w);
  o[4] = f2bf(b.x); o[5] = f2bf(b.y); o[6] = f2bf(b.z); o[7] = f2bf(b.w);
  *(short8*)dst = o;
}

// ---------------- prep: V[4096,1024] f32 -> Vt[1024,4096] bf16 ----------------
__global__ void transpose_bf16_kernel(const float* __restrict__ V,
                                      short* __restrict__ Vt,
                                      int rows, int cols) {
  __shared__ float tile[64][65];
  int n0 = blockIdx.x * 64;
  int d0 = blockIdx.y * 64;
  int t = threadIdx.x;
#pragma unroll
  for (int r = 0; r < 16; ++r) {
    int idx = t + 256 * r;
    int rr = idx >> 6, cc = idx & 63;
    tile[rr][cc] = V[(size_t)(n0 + rr) * cols + d0 + cc];
  }
  __syncthreads();
#pragma unroll
  for (int r = 0; r < 16; ++r) {
    int idx = t + 256 * r;
    int dd = idx >> 6, nn = idx & 63;
    Vt[(size_t)(d0 + dd) * rows + n0 + nn] = f2bf(tile[nn][dd]);
  }
}

// ======== GEMM1: m201-style 8-phase, S[8192,4096](bf16) = Xb x Kb^T ========
// BM=BN=256, BK=64, 8 waves (2x4), per-wave 128x64, 16x16x32 MFMA.
// LDS: 2 bufs x {A: 2 halves [128][64], B: 2 halves [128][64]} = 128 KiB.
// 4 phases/K-tile, one C-quadrant each; staging: A(t+1)->nbuf at p1/p2,
// B(t+2)->buf at p3/p4 (B regions' last read is p1/p2); vmcnt(4) at p4
// certifies all of t+1 with >=2 phases of slack. VMC always just before BAR.
__global__ __launch_bounds__(512, 2) void gemm1_kernel(
    const short* __restrict__ A, const short* __restrict__ B,
    short* __restrict__ S, float* __restrict__ rowss) {
  constexpr int K = 1024, N = 4096, NT = K / 64;
  __shared__ char lds[2 * 65536];  // buf: A halves @0,@16384; B @32768,@49152
  const int t = threadIdx.x, lane = t & 63, w = t >> 6;
  const int wm = w >> 2, wn = w & 3;
  const int idx = lane & 15, g = lane >> 4;
  const int bid = blockIdx.x;
  const int id2 = (bid & 7) * 64 + (bid >> 3);  // 512 blocks, bijective
  const int row0 = (id2 >> 4) * 256, col0 = (id2 & 15) * 256;

  // staging (verified 0-conflict): thread t -> byte t*16 of a 64-row round;
  // content = logical 16B-slot (t&7)^(row&7), row = t>>3
  const int sxor = ((t & 7) ^ ((t >> 3) & 7)) * 8;
  const short* gA = A + (size_t)(row0 + (t >> 3)) * K + sxor;
  const short* gB = B + (size_t)(col0 + (t >> 3)) * K + sxor;

  auto STGA = [&](int buf, int h, int T) {  // half h = rows h*128..+127
#pragma unroll
    for (int r = 0; r < 2; ++r)
      gload16(gA + (size_t)(h * 128 + r * 64) * K + T * 64,
              &lds[buf * 65536 + h * 16384 + r * 8192 + t * 16]);
  };
  auto STGB = [&](int buf, int h, int T) {
#pragma unroll
    for (int r = 0; r < 2; ++r)
      gload16(gB + (size_t)(h * 128 + r * 64) * K + T * 64,
              &lds[buf * 65536 + 32768 + h * 16384 + r * 8192 + t * 16]);
  };

  // reads: logical slot q=ks*4+g of row r at phys slot q^(r&7); r&7==idx&7
  const int xv = (idx & 7) << 4;
  short8 a[4][2], b0[2][2], b1[2][2];
  auto LDA = [&](int buf, int qm) {
#pragma unroll
    for (int f = 0; f < 4; ++f)
#pragma unroll
      for (int ks = 0; ks < 2; ++ks) {
        const int rl = qm * 64 + f * 16 + idx;  // local row in half wm
        a[f][ks] = *(const short8*)&lds[buf * 65536 + wm * 16384 + rl * 128 +
                                        ((ks * 64 + g * 16) ^ xv)];
      }
  };
  auto LDB = [&](int buf, int qn, short8(&bb)[2][2]) {
#pragma unroll
    for (int f = 0; f < 2; ++f)
#pragma unroll
      for (int ks = 0; ks < 2; ++ks) {
        const int cl = (wn & 1) * 64 + qn * 32 + f * 16 + idx;  // in half wn>>1
        bb[f][ks] = *(const short8*)&lds[buf * 65536 + 32768 + (wn >> 1) * 16384 +
                                         cl * 128 + ((ks * 64 + g * 16) ^ xv)];
      }
  };

  f32x4 acc[8][4] = {};  // [qm*4+f][qn*2+f2]
  auto MFQ = [&](int qm, int qn, short8(&bb)[2][2]) {
    __builtin_amdgcn_s_setprio(1);
#pragma unroll
    for (int ks = 0; ks < 2; ++ks)
#pragma unroll
      for (int f = 0; f < 4; ++f)
#pragma unroll
        for (int f2 = 0; f2 < 2; ++f2)
          acc[qm * 4 + f][qn * 2 + f2] = __builtin_amdgcn_mfma_f32_16x16x32_bf16(
              a[f][ks], bb[f2][ks], acc[qm * 4 + f][qn * 2 + f2], 0, 0, 0);
    __builtin_amdgcn_s_setprio(0);
  };

  // prologue: tile0 all 4 halves -> buf0; B halves of tile1 -> buf1;
  // vmcnt(4) certifies tile0 (leaves tile1's B in flight)
  STGA(0, 0, 0); STGA(0, 1, 0);
  STGB(0, 0, 0); STGB(0, 1, 0);
  STGB(1, 0, 1); STGB(1, 1, 1);
  VMC(4);
  BAR;

  for (int tb = 0; tb < NT; tb += 2) {
#pragma unroll
    for (int u = 0; u < 2; ++u) {
      const int T = tb + u, buf = u, nbuf = u ^ 1;
      const bool more1 = (T + 1 < NT), more2 = (T + 2 < NT);
      // p1: quadrant (0,0); stage A0(t+1)
      LDA(buf, 0);
      LDB(buf, 0, b0);
      if (more1) STGA(nbuf, 0, T + 1);
      BAR; LGKM0; MFQ(0, 0, b0); BAR;
      // p2: quadrant (0,1); stage A1(t+1)
      LDB(buf, 1, b1);
      if (more1) STGA(nbuf, 1, T + 1);
      BAR; LGKM0; MFQ(0, 1, b1); BAR;
      // p3: quadrant (1,1); stage B0(t+2) into buf (B0 last read at p1)
      LDA(buf, 1);
      if (more2) STGB(buf, 0, T + 2);
      BAR; LGKM0; MFQ(1, 1, b1); BAR;
      // p4: quadrant (1,0), no new reads; stage B1(t+2) (last read at p2)
      if (more2) STGB(buf, 1, T + 2);
      BAR;
      MFQ(1, 0, b0);
      if (more2) {
        VMC(4);  // certify all 4 halves of t+1; leave B(t+2) in flight
        BAR;
      } else if (more1) {
        VMC(0);  // tail: drain A(t+1) (+B(t+1) already queued)
        BAR;
      }
    }
  }

  // epilogue: C/D col=idx, row=4g+j within each 16x16 frag
#pragma unroll
  for (int mf = 0; mf < 8; ++mf) {
#pragma unroll
    for (int j = 0; j < 4; ++j) {
      const int row = row0 + wm * 128 + (mf >> 2) * 64 + (mf & 3) * 16 + g * 4 + j;
      float ss = 0.f;
#pragma unroll
      for (int nf = 0; nf < 4; ++nf) {
        const float v = acc[mf][nf][j];
        ss += v * v;
        const int col = col0 + wn * 64 + (nf >> 1) * 32 + (nf & 1) * 16 + idx;
        S[(size_t)row * N + col] = f2bf(v);
      }
      ss += __shfl_xor(ss, 1);
      ss += __shfl_xor(ss, 2);
      ss += __shfl_xor(ss, 4);
      ss += __shfl_xor(ss, 8);
      if (idx == 0) atomicAdd(&rowss[row], ss);
    }
  }
}

// ======== GEMM2 (R5-proven): out[8192,1024](f32) = S x Vt^T ========
// BM=256, BN=128, BK=64, 8 waves (4x2), dbuf LDS 96 KiB, 2 bar/tile.
__global__ __launch_bounds__(512, 2) void gemm2_kernel(
    const short* __restrict__ A, const short* __restrict__ B,
    float* __restrict__ C) {
  constexpr int K = 4096, N = 1024, NT = K / 64;
  __shared__ char lds[2 * 49152];  // per buf: A 32K @0, B 16K @32768
  const int t = threadIdx.x, lane = t & 63, w = t >> 6;
  const int wm = w >> 1, wn = w & 1;
  const int idx = lane & 15, g = lane >> 4;
  const int bid = blockIdx.x;
  const int id2 = (bid & 7) * 32 + (bid >> 3);  // 256 blocks
  const int row0 = (id2 >> 3) * 256, col0 = (id2 & 7) * 128;

  const int srow = t >> 3;
  const int ksl = (t & 7) ^ (srow & 7);
  const short* gA = A + (size_t)(row0 + srow) * K + ksl * 8;
  const short* gB = B + (size_t)(col0 + srow) * K + ksl * 8;

  auto stageAr = [&](int buf, int fr, int kt) {  // one 8 KiB round
    gload16(gA + (size_t)(fr)*K + kt, &lds[buf * 49152 + fr * 128 + t * 16]);
  };
  auto stageB = [&](int buf, int kt) {  // both rounds (16 KiB)
#pragma unroll
    for (int r = 0; r < 2; ++r)
      gload16(gB + (size_t)(r * 64) * K + kt,
              &lds[buf * 49152 + 32768 + r * 8192 + t * 16]);
  };

  const int xv = (idx & 7) << 4;
  short8 a[2][2], b[4][2];
  auto lda = [&](int buf, int mh) {
#pragma unroll
    for (int f = 0; f < 2; ++f)
#pragma unroll
      for (int ks = 0; ks < 2; ++ks) {
        int row = mh * 128 + wm * 32 + f * 16 + idx;
        int byte = row * 128 + ((ks * 64 + g * 16) ^ xv);
        a[f][ks] = *(const short8*)&lds[buf * 49152 + byte];
      }
  };
  auto ldb = [&](int buf) {
#pragma unroll
    for (int nf = 0; nf < 4; ++nf)
#pragma unroll
      for (int ks = 0; ks < 2; ++ks) {
        int col = wn * 64 + nf * 16 + idx;
        int byte = col * 128 + ((ks * 64 + g * 16) ^ xv);
        b[nf][ks] = *(const short8*)&lds[buf * 49152 + 32768 + byte];
      }
  };

  f32x4 acc[4][4] = {};
  auto MF = [&](int mh) {
    __builtin_amdgcn_s_setprio(1);
#pragma unroll
    for (int ks = 0; ks < 2; ++ks)
#pragma unroll
      for (int f = 0; f < 2; ++f)
#pragma unroll
        for (int nf = 0; nf < 4; ++nf)
          acc[mh * 2 + f][nf] = __builtin_amdgcn_mfma_f32_16x16x32_bf16(
              a[f][ks], b[nf][ks], acc[mh * 2 + f][nf], 0, 0, 0);
    __builtin_amdgcn_s_setprio(0);
  };

  // prologue: stage tile 0 [B,A0,A1,A2,A3]; certify B,A0,A1 (4 of 6)
  stageB(0, 0);
  stageAr(0, 0, 0);
  stageAr(0, 64, 0);
  stageAr(0, 128, 0);
  stageAr(0, 192, 0);
  VMC(2);
  BAR;

  for (int tb = 0; tb < NT; tb += 2) {
#pragma unroll
    for (int u = 0; u < 2; ++u) {
      const int T = tb + u, buf = u, nbuf = u ^ 1;
      const int kt1 = (T + 1) * 64;
      const bool more = (T + 1 < NT);
      // p1: m-half 0 (uses all B) — B,A0,A1 certified at boundary
      ldb(buf); lda(buf, 0);
      if (more) { stageB(nbuf, kt1); stageAr(nbuf, 0, kt1); stageAr(nbuf, 64, kt1); }
      MF(0);
      // mid-tile: certify A2,A3(t) across waves
      if (more) { VMC(4); } else { VMC(0); }
      BAR;
      // p2: m-half 1
      lda(buf, 1);
      if (more) { stageAr(nbuf, 128, kt1); stageAr(nbuf, 192, kt1); }
      MF(1);
      if (more) {
        VMC(2);  // certify B,A0,A1(t+1)
        BAR;
      }
    }
  }

#pragma unroll
  for (int mf = 0; mf < 4; ++mf)
#pragma unroll
    for (int j = 0; j < 4; ++j) {
      const int row = row0 + wm * 32 + (mf & 1) * 16 + (mf >> 1) * 128 + g * 4 + j;
#pragma unroll
      for (int nf = 0; nf < 4; ++nf)
        C[(size_t)row * N + col0 + wn * 64 + nf * 16 + idx] = acc[mf][nf][j];
    }
}

// ---------------- normalize + exact GELU ----------------
__global__ void norm_gelu_kernel(short* __restrict__ S,
                                 const float* __restrict__ rowss, int total8) {
  int i = blockIdx.x * blockDim.x + threadIdx.x;
  if (i >= total8) return;
  size_t base = (size_t)i * 8;
  int row = (int)(base >> 12);
  float scale = 64.0f * rsqrtf(rowss[row]);
  short8 v = *(short8*)(S + base);
  short8 o;
#pragma unroll
  for (int k = 0; k < 8; ++k) {
    float x = bf2f(v[k]) * scale;
    float gl = 0.5f * x * (1.0f + erff(x * 0.70710678118654752f));
    o[k] = f2bf(gl);
  }
  *(short8*)(S + base) = o;
}

extern "C" void kernel_launch(void* const* d_in, const int* in_sizes, int n_in,
                              void* d_out, int out_size, void* d_ws,
                              size_t ws_size, hipStream_t stream) {
  const float* X = (const float*)d_in[0];
  const float* Kp = (const float*)d_in[1];
  const float* Vp = (const float*)d_in[2];
  float* out = (float*)d_out;

  const int M = 8192, D1 = 1024, Nn = 4096, D2 = 1024;

  char* ws = (char*)d_ws;
  short* Xb = (short*)ws; ws += (size_t)M * D1 * 2;
  short* Kb = (short*)ws; ws += (size_t)Nn * D1 * 2;
  short* Vt = (short*)ws; ws += (size_t)D2 * Nn * 2;
  short* S  = (short*)ws; ws += (size_t)M * Nn * 2;
  float* rowss = (float*)ws;
  (void)ws_size;

  hipMemsetAsync(rowss, 0, M * sizeof(float), stream);
  const int n8x = M * D1 / 8, n8k = Nn * D1 / 8;
  cvt2_kernel<<<(n8x + n8k + 255) / 256, 256, 0, stream>>>(X, Kp, Xb, Kb, n8x, n8x + n8k);
  transpose_bf16_kernel<<<dim3(Nn / 64, D2 / 64), 256, 0, stream>>>(Vp, Vt, Nn, D2);

  gemm1_kernel<<<512, 512, 0, stream>>>(Xb, Kb, S, rowss);
  norm_gelu_kernel<<<(M * Nn / 8 + 255) / 256, 256, 0, stream>>>(S, rowss, M * Nn / 8);
  gemm2_kernel<<<256, 512, 0, stream>>>(S, Vt, out);
}

// Round 13
// 195.191 us; speedup vs baseline: 1.3526x; 1.0148x over previous
//
#include <hip/hip_runtime.h>
#include <hip/hip_bf16.h>
#include <math.h>
#include <stdint.h>

typedef __attribute__((ext_vector_type(8))) short short8;
typedef __attribute__((ext_vector_type(4))) float f32x4;

__device__ inline short f2bf(float x) {
  union { float f; uint32_t u; } c; c.f = x;
  uint32_t r = (c.u + 0x7FFFu + ((c.u >> 16) & 1u)) >> 16;
  return (short)(uint16_t)r;
}
__device__ inline float bf2f(short s) {
  union { uint32_t u; float f; } c; c.u = ((uint32_t)(uint16_t)s) << 16;
  return c.f;
}

__device__ inline void gload16(const short* src, const char* ldsdst) {
  __builtin_amdgcn_global_load_lds(
      (const __attribute__((address_space(1))) void*)src,
      (__attribute__((address_space(3))) void*)ldsdst, 16, 0, 0);
}

#define BAR __builtin_amdgcn_s_barrier()
#define VMC(n) asm volatile("s_waitcnt vmcnt(" #n ")" ::: "memory")
#define LGKMW asm volatile("s_waitcnt lgkmcnt(0)" ::: "memory")

// ---------------- prep: f32 -> bf16 for X and Kp in one launch ----------------
__global__ void cvt2_kernel(const float* __restrict__ X, const float* __restrict__ Kp,
                            short* __restrict__ Xb, short* __restrict__ Kb,
                            int n8x, int n8tot) {
  int i = blockIdx.x * blockDim.x + threadIdx.x;
  if (i >= n8tot) return;
  const float* src = (i < n8x) ? X + (size_t)i * 8 : Kp + (size_t)(i - n8x) * 8;
  short* dst = (i < n8x) ? Xb + (size_t)i * 8 : Kb + (size_t)(i - n8x) * 8;
  const float4* p = (const float4*)src;
  float4 a = p[0], b = p[1];
  short8 o;
  o[0] = f2bf(a.x); o[1] = f2bf(a.y); o[2] = f2bf(a.z); o[3] = f2bf(a.w);
  o[4] = f2bf(b.x); o[5] = f2bf(b.y); o[6] = f2bf(b.z); o[7] = f2bf(b.w);
  *(short8*)dst = o;
}

// ---------------- prep: V[4096,1024] f32 -> Vt[1024,4096] bf16 ----------------
__global__ void transpose_bf16_kernel(const float* __restrict__ V,
                                      short* __restrict__ Vt,
                                      int rows, int cols) {
  __shared__ float tile[64][65];
  int n0 = blockIdx.x * 64;
  int d0 = blockIdx.y * 64;
  int t = threadIdx.x;
#pragma unroll
  for (int r = 0; r < 16; ++r) {
    int idx = t + 256 * r;
    int rr = idx >> 6, cc = idx & 63;
    tile[rr][cc] = V[(size_t)(n0 + rr) * cols + d0 + cc];
  }
  __syncthreads();
#pragma unroll
  for (int r = 0; r < 16; ++r) {
    int idx = t + 256 * r;
    int dd = idx >> 6, nn = idx & 63;
    Vt[(size_t)(d0 + dd) * rows + n0 + nn] = f2bf(tile[nn][dd]);
  }
}

// ======== GEMM1 (R5-proven): S[8192,4096](bf16) = Xb x Kb^T ========
// BM=BN=256, BK=64, 8 waves (2x4), dbuf LDS 128 KiB.
// 2 barriers + 2 counted vmcnt per K-tile; every VMC immediately precedes BAR.
__global__ __launch_bounds__(512, 2) void gemm1_kernel(
    const short* __restrict__ A, const short* __restrict__ B,
    short* __restrict__ S, float* __restrict__ rowss) {
  constexpr int K = 1024, N = 4096, NT = K / 64;
  __shared__ char lds[2 * 65536];  // per buf: A 32K @0, B 32K @32768
  const int t = threadIdx.x, lane = t & 63, w = t >> 6;
  const int wm = w >> 2, wn = w & 3;
  const int idx = lane & 15, g = lane >> 4;
  const int bid = blockIdx.x;
  const int id2 = (bid & 7) * 64 + (bid >> 3);  // 512 blocks, bijective
  const int row0 = (id2 >> 4) * 256, col0 = (id2 & 15) * 256;

  const int srow = t >> 3;               // 0..63 within a round
  const int ksl = (t & 7) ^ (srow & 7);  // pre-swizzled 16B k-slot
  const short* gA = A + (size_t)(row0 + srow) * K + ksl * 8;
  const short* gB = B + (size_t)(col0 + srow) * K + ksl * 8;

  auto stageA = [&](int buf, int frow, int kt) {
#pragma unroll
    for (int r = 0; r < 2; ++r)
      gload16(gA + (size_t)(frow + r * 64) * K + kt,
              &lds[buf * 65536 + (frow + r * 64) * 128 + t * 16]);
  };
  auto stageB = [&](int buf, int frow, int kt) {
#pragma unroll
    for (int r = 0; r < 2; ++r)
      gload16(gB + (size_t)(frow + r * 64) * K + kt,
              &lds[buf * 65536 + 32768 + (frow + r * 64) * 128 + t * 16]);
  };

  const int xv = (idx & 7) << 4;
  short8 a[4][2], b[2][2][2];
  auto lda = [&](int buf, int mh) {
#pragma unroll
    for (int f = 0; f < 4; ++f)
#pragma unroll
      for (int ks = 0; ks < 2; ++ks) {
        int row = mh * 128 + wm * 64 + f * 16 + idx;
        int byte = row * 128 + ((ks * 64 + g * 16) ^ xv);
        a[f][ks] = *(const short8*)&lds[buf * 65536 + byte];
      }
  };
  auto ldb = [&](int buf, int nh) {
#pragma unroll
    for (int nf = 0; nf < 2; ++nf)
#pragma unroll
      for (int ks = 0; ks < 2; ++ks) {
        int col = nh * 128 + wn * 32 + nf * 16 + idx;
        int byte = col * 128 + ((ks * 64 + g * 16) ^ xv);
        b[nh][nf][ks] = *(const short8*)&lds[buf * 65536 + 32768 + byte];
      }
  };

  f32x4 acc[8][4] = {};
  auto MF = [&](int mh, int nh) {
    __builtin_amdgcn_s_setprio(1);
#pragma unroll
    for (int ks = 0; ks < 2; ++ks)
#pragma unroll
      for (int f = 0; f < 4; ++f)
#pragma unroll
        for (int n = 0; n < 2; ++n)
          acc[mh * 4 + f][nh * 2 + n] = __builtin_amdgcn_mfma_f32_16x16x32_bf16(
              a[f][ks], b[nh][n][ks], acc[mh * 4 + f][nh * 2 + n], 0, 0, 0);
    __builtin_amdgcn_s_setprio(0);
  };

  // prologue: stage tile 0 [Alo,Blo,Bhi,Ahi]; certify Alo,Blo,Bhi (6 of 8)
  stageA(0, 0, 0);
  stageB(0, 0, 0);
  stageB(0, 128, 0);
  stageA(0, 128, 0);
  VMC(2);
  BAR;

  for (int tb = 0; tb < NT; tb += 2) {
#pragma unroll
    for (int u = 0; u < 2; ++u) {
      const int T = tb + u, buf = u, nbuf = u ^ 1;
      const int kt1 = (T + 1) * 64;
      const bool more = (T + 1 < NT);
      // p1: quadrant (m0,n0) — Alo,Blo certified at boundary
      lda(buf, 0); ldb(buf, 0);
      if (more) stageA(nbuf, 0, kt1);  // Alo(t+1)
      MF(0, 0);
      // p2: quadrant (m0,n1) — Bhi certified at boundary
      ldb(buf, 1);
      if (more) stageB(nbuf, 0, kt1);  // Blo(t+1)
      MF(0, 1);
      // mid-tile: certify Ahi(t) across waves
      if (more) { VMC(4); } else { VMC(0); }
      BAR;
      // p3: quadrant (m1,n1)
      lda(buf, 1);
      if (more) stageB(nbuf, 128, kt1);  // Bhi(t+1)
      MF(1, 1);
      // p4: quadrant (m1,n0)
      if (more) stageA(nbuf, 128, kt1);  // Ahi(t+1)
      MF(1, 0);
      if (more) {
        VMC(2);  // certify Alo,Blo,Bhi(t+1)
        BAR;     // tile boundary
      }
    }
  }

  // epilogue: C/D col=idx, row=4g+j within the 16x16 frag tile
#pragma unroll
  for (int mf = 0; mf < 8; ++mf) {
#pragma unroll
    for (int j = 0; j < 4; ++j) {
      const int row = row0 + wm * 64 + (mf & 3) * 16 + (mf >> 2) * 128 + g * 4 + j;
      float ss = 0.f;
#pragma unroll
      for (int nf = 0; nf < 4; ++nf) {
        const float v = acc[mf][nf][j];
        ss += v * v;
        const int col = col0 + wn * 32 + (nf & 1) * 16 + (nf >> 1) * 128 + idx;
        S[(size_t)row * N + col] = f2bf(v);
      }
      ss += __shfl_xor(ss, 1);
      ss += __shfl_xor(ss, 2);
      ss += __shfl_xor(ss, 4);
      ss += __shfl_xor(ss, 8);
      if (idx == 0) atomicAdd(&rowss[row], ss);
    }
  }
}

// ======== GEMM2 (new 8-phase): out[8192,1024](f32) = S x Vt^T ========
// BM=256, BN=128, BK=64, 8 waves (4x2), per-wave 64x64, dbuf LDS 96 KiB.
// 2 phases/tile x 16 MFMA; A(t+1)->nbuf at p1; B(t+2)->hot buf at p2 after
// barrier+lgkm drain; counted VMC(2) only at tile end (immediately before BAR).
__global__ __launch_bounds__(512, 2) void gemm2_kernel(
    const short* __restrict__ A, const short* __restrict__ B,
    float* __restrict__ C) {
  constexpr int K = 4096, N = 1024, NT = K / 64;
  __shared__ char lds[2 * 49152];  // per buf: A 32K @0 (4 rounds), B 16K @32768
  const int t = threadIdx.x, lane = t & 63, w = t >> 6;
  const int wm = w >> 1, wn = w & 1;
  const int idx = lane & 15, g = lane >> 4;
  const int bid = blockIdx.x;
  const int id2 = (bid & 7) * 32 + (bid >> 3);  // 256 blocks, 1/CU
  const int row0 = (id2 >> 3) * 256, col0 = (id2 & 7) * 128;

  const int srow = t >> 3;
  const int ksl = (t & 7) ^ (srow & 7);
  const short* gA = A + (size_t)(row0 + srow) * K + ksl * 8;
  const short* gB = B + (size_t)(col0 + srow) * K + ksl * 8;

  auto STGA = [&](int buf, int T) {  // all 4 rounds (32 KiB)
#pragma unroll
    for (int r = 0; r < 4; ++r)
      gload16(gA + (size_t)(r * 64) * K + T * 64,
              &lds[buf * 49152 + r * 8192 + t * 16]);
  };
  auto STGB = [&](int buf, int T) {  // 2 rounds (16 KiB)
#pragma unroll
    for (int r = 0; r < 2; ++r)
      gload16(gB + (size_t)(r * 64) * K + T * 64,
              &lds[buf * 49152 + 32768 + r * 8192 + t * 16]);
  };

  const int xv = (idx & 7) << 4;
  short8 a[4][2], b[2][2];
  auto LDA = [&](int buf) {  // all 4 m-frags (rows wm*64..+63)
#pragma unroll
    for (int f = 0; f < 4; ++f)
#pragma unroll
      for (int ks = 0; ks < 2; ++ks) {
        int row = wm * 64 + f * 16 + idx;
        a[f][ks] = *(const short8*)&lds[buf * 49152 + row * 128 +
                                        ((ks * 64 + g * 16) ^ xv)];
      }
  };
  auto LDB = [&](int buf, int nh) {  // 2 n-frags of half nh
#pragma unroll
    for (int f = 0; f < 2; ++f)
#pragma unroll
      for (int ks = 0; ks < 2; ++ks) {
        int col = wn * 64 + nh * 32 + f * 16 + idx;
        b[f][ks] = *(const short8*)&lds[buf * 49152 + 32768 + col * 128 +
                                        ((ks * 64 + g * 16) ^ xv)];
      }
  };

  f32x4 acc[4][4] = {};
  auto MFQ = [&](int nh) {  // 16 MFMA: 4m x 2n x 2ks
    __builtin_amdgcn_s_setprio(1);
#pragma unroll
    for (int ks = 0; ks < 2; ++ks)
#pragma unroll
      for (int f = 0; f < 4; ++f)
#pragma unroll
        for (int f2 = 0; f2 < 2; ++f2)
          acc[f][nh * 2 + f2] = __builtin_amdgcn_mfma_f32_16x16x32_bf16(
              a[f][ks], b[f2][ks], acc[f][nh * 2 + f2], 0, 0, 0);
    __builtin_amdgcn_s_setprio(0);
  };

  // prologue: A(0),B(0)->buf0, B(1)->buf1; certify A(0),B(0) (leave B(1))
  STGA(0, 0);
  STGB(0, 0);
  STGB(1, 1);
  VMC(2);
  BAR;

  for (int tb = 0; tb < NT; tb += 2) {
#pragma unroll
    for (int u = 0; u < 2; ++u) {
      const int T = tb + u, buf = u, nbuf = u ^ 1;
      const bool more1 = (T + 1 < NT), more2 = (T + 2 < NT);
      // p1: n-half 0; stage A(t+1) cross-buffer
      LDA(buf);
      LDB(buf, 0);
      if (more1) STGA(nbuf, T + 1);
      BAR;
      LGKMW;
      MFQ(0);
      BAR;
      // p2: n-half 1; stage B(t+2) into hot buffer AFTER barrier+lgkm drain
      LDB(buf, 1);
      BAR;
      LGKMW;  // all waves' B(t) reads complete before DMA overwrite below
      if (more2) STGB(buf, T + 2);
      MFQ(1);
      if (more2) { VMC(2); } else if (more1) { VMC(0); }
      BAR;
    }
  }

  // epilogue: C/D col=idx, row=4g+j within each 16x16 frag
#pragma unroll
  for (int mf = 0; mf < 4; ++mf)
#pragma unroll
    for (int j = 0; j < 4; ++j) {
      const int row = row0 + wm * 64 + mf * 16 + g * 4 + j;
#pragma unroll
      for (int nf = 0; nf < 4; ++nf)
        C[(size_t)row * N + col0 + wn * 64 + nf * 16 + idx] = acc[mf][nf][j];
    }
}

// ---------------- normalize + exact GELU ----------------
__global__ void norm_gelu_kernel(short* __restrict__ S,
                                 const float* __restrict__ rowss, int total8) {
  int i = blockIdx.x * blockDim.x + threadIdx.x;
  if (i >= total8) return;
  size_t base = (size_t)i * 8;
  int row = (int)(base >> 12);
  float scale = 64.0f * rsqrtf(rowss[row]);
  short8 v = *(short8*)(S + base);
  short8 o;
#pragma unroll
  for (int k = 0; k < 8; ++k) {
    float x = bf2f(v[k]) * scale;
    float gl = 0.5f * x * (1.0f + erff(x * 0.70710678118654752f));
    o[k] = f2bf(gl);
  }
  *(short8*)(S + base) = o;
}

extern "C" void kernel_launch(void* const* d_in, const int* in_sizes, int n_in,
                              void* d_out, int out_size, void* d_ws,
                              size_t ws_size, hipStream_t stream) {
  const float* X = (const float*)d_in[0];
  const float* Kp = (const float*)d_in[1];
  const float* Vp = (const float*)d_in[2];
  float* out = (float*)d_out;

  const int M = 8192, D1 = 1024, Nn = 4096, D2 = 1024;

  char* ws = (char*)d_ws;
  short* Xb = (short*)ws; ws += (size_t)M * D1 * 2;
  short* Kb = (short*)ws; ws += (size_t)Nn * D1 * 2;
  short* Vt = (short*)ws; ws += (size_t)D2 * Nn * 2;
  short* S  = (short*)ws; ws += (size_t)M * Nn * 2;
  float* rowss = (float*)ws;
  (void)ws_size;

  hipMemsetAsync(rowss, 0, M * sizeof(float), stream);
  const int n8x = M * D1 / 8, n8k = Nn * D1 / 8;
  cvt2_kernel<<<(n8x + n8k + 255) / 256, 256, 0, stream>>>(X, Kp, Xb, Kb, n8x, n8x + n8k);
  transpose_bf16_kernel<<<dim3(Nn / 64, D2 / 64), 256, 0, stream>>>(Vp, Vt, Nn, D2);

  gemm1_kernel<<<512, 512, 0, stream>>>(Xb, Kb, S, rowss);
  norm_gelu_kernel<<<(M * Nn / 8 + 255) / 256, 256, 0, stream>>>(S, rowss, M * Nn / 8);
  gemm2_kernel<<<256, 512, 0, stream>>>(S, Vt, out);
}